// Round 1
// baseline (175.036 us; speedup 1.0000x reference)
//
#include <hip/hip_runtime.h>
#include <cstdint>

// Shapes from the reference setup (fixed by the harness):
// u, delta, z: (b=2, d=1024, l=2048) fp32; A: (d, n=16); B, C: (b, n, l); D: (d,)
constexpr int kD = 1024;
constexpr int kN = 16;
constexpr int kL = 2048;
constexpr int BLOCK = 256;
constexpr int T  = kL / BLOCK;   // 8 timesteps per thread
constexpr int NW = BLOCK / 64;   // 4 waves per block
constexpr float LOG2E = 1.44269504088896340736f;

__device__ __forceinline__ float fast_exp2(float x) { return __builtin_amdgcn_exp2f(x); }
__device__ __forceinline__ float fast_exp(float x)  { return __builtin_amdgcn_exp2f(x * LOG2E); }
__device__ __forceinline__ float softplus_f(float x) {
  // log1p(exp(x)), stable for large x; tolerance is loose (3.12 absmax)
  return (x > 20.0f) ? x : __logf(1.0f + fast_exp(x));
}

__global__ __launch_bounds__(BLOCK)
void selscan_kernel(const float* __restrict__ u,  const float* __restrict__ dl,
                    const float* __restrict__ A,  const float* __restrict__ Bm,
                    const float* __restrict__ Cm, const float* __restrict__ Dv,
                    const float* __restrict__ zm, float* __restrict__ out)
{
  const int row  = blockIdx.x;          // b*kD + d
  const int b    = row / kD;
  const int d    = row - b * kD;
  const int tid  = threadIdx.x;
  const int lane = tid & 63;
  const int wid  = tid >> 6;

  // A row for this d, pre-scaled by log2(e) so the inner loop is one v_exp_f32
  float Ar[kN];
  {
    const float4* A4 = reinterpret_cast<const float4*>(A + (size_t)d * kN);
    #pragma unroll
    for (int i = 0; i < kN / 4; ++i) {
      float4 v = A4[i];
      Ar[4*i+0] = v.x * LOG2E; Ar[4*i+1] = v.y * LOG2E;
      Ar[4*i+2] = v.z * LOG2E; Ar[4*i+3] = v.w * LOG2E;
    }
  }

  const size_t roff = (size_t)row * kL;
  const float4* u4 = reinterpret_cast<const float4*>(u  + roff);
  const float4* d4 = reinterpret_cast<const float4*>(dl + roff);

  // Per-thread timestep chunk [tid*T, tid*T+T): u, softplus(delta), delta*u in regs
  float uu[T], sp[T], du[T];
  {
    float4 a0 = u4[tid*2+0], a1 = u4[tid*2+1];
    uu[0]=a0.x; uu[1]=a0.y; uu[2]=a0.z; uu[3]=a0.w;
    uu[4]=a1.x; uu[5]=a1.y; uu[6]=a1.z; uu[7]=a1.w;
    float4 b0 = d4[tid*2+0], b1 = d4[tid*2+1];
    float dv[T] = {b0.x,b0.y,b0.z,b0.w,b1.x,b1.y,b1.z,b1.w};
    #pragma unroll
    for (int i = 0; i < T; ++i) { sp[i] = softplus_f(dv[i]); du[i] = sp[i] * uu[i]; }
  }

  const float4* B4 = reinterpret_cast<const float4*>(Bm + (size_t)b * kN * kL);
  const float4* C4 = reinterpret_cast<const float4*>(Cm + (size_t)b * kN * kL);

  // ---- Pass A: local scan from zero -> per-state chunk aggregates (prod a, h_end)
  float cA[kN], cX[kN];
  #pragma unroll
  for (int n = 0; n < kN; ++n) {
    float4 b0 = B4[n*(kL/4) + tid*2 + 0];
    float4 b1 = B4[n*(kL/4) + tid*2 + 1];
    float Bv[T] = {b0.x,b0.y,b0.z,b0.w,b1.x,b1.y,b1.z,b1.w};
    float ap = 1.0f, h = 0.0f;
    #pragma unroll
    for (int i = 0; i < T; ++i) {
      float a = fast_exp2(sp[i] * Ar[n]);
      h  = a * h + du[i] * Bv[i];
      ap *= a;
    }
    cA[n] = ap; cX[n] = h;
  }

  // ---- Wave-level inclusive scan over lanes (Hillis-Steele, width 64)
  #pragma unroll
  for (int n = 0; n < kN; ++n) {
    float a = cA[n], x = cX[n];
    #pragma unroll
    for (int off = 1; off < 64; off <<= 1) {
      float au = __shfl_up(a, (unsigned)off, 64);
      float xu = __shfl_up(x, (unsigned)off, 64);
      if (lane >= off) { x = a * xu + x; a = a * au; }
    }
    cA[n] = a; cX[n] = x;
  }

  // ---- Cross-wave scan (4 waves) through LDS
  __shared__ float sA[NW][kN], sX[NW][kN], eA[NW][kN], eX[NW][kN];
  if (lane == 63) {
    #pragma unroll
    for (int n = 0; n < kN; ++n) { sA[wid][n] = cA[n]; sX[wid][n] = cX[n]; }
  }
  __syncthreads();
  if (tid < kN) {
    const int n = tid;
    float a = 1.0f, x = 0.0f;
    #pragma unroll
    for (int w = 0; w < NW; ++w) {
      eA[w][n] = a; eX[w][n] = x;          // exclusive prefix for wave w
      float aw = sA[w][n], xw = sX[w][n];
      x = aw * x + xw;
      a = a * aw;
    }
  }
  __syncthreads();

  // ---- Per-thread initial state h_{start-1}[n]
  float h0[kN];
  #pragma unroll
  for (int n = 0; n < kN; ++n) {
    float al = __shfl_up(cA[n], 1u, 64);   // lane-exclusive = inclusive shifted by 1
    float xl = __shfl_up(cX[n], 1u, 64);
    if (lane == 0) { al = 1.0f; xl = 0.0f; }
    h0[n] = al * eX[wid][n] + xl;          // combine(wave-exclusive, lane-exclusive).X
  }

  // ---- Pass B: rescan with correct init, fuse y = sum_n C*h
  float y[T];
  #pragma unroll
  for (int i = 0; i < T; ++i) y[i] = 0.0f;
  #pragma unroll
  for (int n = 0; n < kN; ++n) {
    float4 b0 = B4[n*(kL/4) + tid*2 + 0];
    float4 b1 = B4[n*(kL/4) + tid*2 + 1];
    float4 c0 = C4[n*(kL/4) + tid*2 + 0];
    float4 c1 = C4[n*(kL/4) + tid*2 + 1];
    float Bv[T] = {b0.x,b0.y,b0.z,b0.w,b1.x,b1.y,b1.z,b1.w};
    float Cv[T] = {c0.x,c0.y,c0.z,c0.w,c1.x,c1.y,c1.z,c1.w};
    float h = h0[n];
    #pragma unroll
    for (int i = 0; i < T; ++i) {
      float a = fast_exp2(sp[i] * Ar[n]);
      h = a * h + du[i] * Bv[i];
      y[i] += Cv[i] * h;
    }
  }

  // ---- Epilogue: + u*D, * silu(z), store
  const float Dd = Dv[d];
  const float4* z4 = reinterpret_cast<const float4*>(zm + roff);
  float4 z0 = z4[tid*2+0], z1 = z4[tid*2+1];
  float zv[T] = {z0.x,z0.y,z0.z,z0.w,z1.x,z1.y,z1.z,z1.w};
  float ov[T];
  #pragma unroll
  for (int i = 0; i < T; ++i) {
    float yy  = y[i] + uu[i] * Dd;
    float sig = 1.0f / (1.0f + fast_exp(-zv[i]));
    ov[i] = yy * zv[i] * sig;
  }
  float4* out4 = reinterpret_cast<float4*>(out + roff);
  out4[tid*2+0] = make_float4(ov[0], ov[1], ov[2], ov[3]);
  out4[tid*2+1] = make_float4(ov[4], ov[5], ov[6], ov[7]);
}

extern "C" void kernel_launch(void* const* d_in, const int* in_sizes, int n_in,
                              void* d_out, int out_size, void* d_ws, size_t ws_size,
                              hipStream_t stream)
{
  const float* u  = (const float*)d_in[0];
  const float* dl = (const float*)d_in[1];
  const float* A  = (const float*)d_in[2];
  const float* Bm = (const float*)d_in[3];
  const float* Cm = (const float*)d_in[4];
  const float* Dv = (const float*)d_in[5];
  const float* zm = (const float*)d_in[6];
  float* out = (float*)d_out;
  const int rows = in_sizes[0] / kL;   // b*d = 2048
  selscan_kernel<<<rows, BLOCK, 0, stream>>>(u, dl, A, Bm, Cm, Dv, zm, out);
}